// Round 4
// baseline (649.228 us; speedup 1.0000x reference)
//
#include <hip/hip_runtime.h>
#include <hip/hip_bf16.h>
#include <stdint.h>

#define T_DIM 256
#define B_DIM 64
#define DICO  8192
#define EMB   256
#define LAT   256
#define M_DIM (T_DIM*B_DIM)   /* 16384 */

#define BM 128
#define BN 256
#define BK 64
#define KSPLIT 2
#define KCHUNK (DICO/KSPLIT)  /* 4096 */
#define NKS (KCHUNK/BK)       /* 64 */

typedef short  bf16x8 __attribute__((ext_vector_type(8)));
typedef float  f32x4  __attribute__((ext_vector_type(4)));
typedef _Float16 f16x2 __attribute__((ext_vector_type(2)));

__device__ __forceinline__ ushort f2bf(float f) {
  uint32_t u = __float_as_uint(f);
  u += 0x7FFFu + ((u >> 16) & 1u);     // round-to-nearest-even
  return (ushort)(u >> 16);
}

__device__ __forceinline__ void glds16(const void* g, void* l) {
  __builtin_amdgcn_global_load_lds(
      (const __attribute__((address_space(1))) uint32_t*)g,
      (__attribute__((address_space(3))) uint32_t*)l, 16, 0, 0);
}

// ---------------- Kernel 1: Wct[n][k] = sum_e W_emb[k][e] * W_enc[e][n], bf16, n-major
__global__ void wct_kernel(const float* __restrict__ Wemb, const float* __restrict__ Wenc,
                           ushort* __restrict__ wct) {
  const int n  = threadIdx.x;          // 0..255
  const int d0 = blockIdx.x * 32;      // 256 blocks
  __shared__ float we[32 * 256];
  __shared__ float tr[32 * 257];
  #pragma unroll
  for (int r = 0; r < 32; ++r) we[r*256 + n] = Wemb[(size_t)(d0 + r)*EMB + n];
  __syncthreads();
  float acc[32];
  #pragma unroll
  for (int d = 0; d < 32; ++d) acc[d] = 0.f;
  #pragma unroll 4
  for (int e = 0; e < 256; ++e) {
    float wv = Wenc[e*LAT + n];
    #pragma unroll
    for (int d = 0; d < 32; ++d) acc[d] += we[d*256 + e] * wv;   // LDS broadcast
  }
  #pragma unroll
  for (int d = 0; d < 32; ++d) tr[d*257 + n] = acc[d];
  __syncthreads();
  const int nn0 = n >> 2, kc = n & 3;
  #pragma unroll
  for (int p = 0; p < 4; ++p) {
    int nn = p*64 + nn0;
    bf16x8 v;
    #pragma unroll
    for (int j = 0; j < 8; ++j) v[j] = (short)f2bf(tr[(kc*8 + j)*257 + nn]);
    *(bf16x8*)(wct + (size_t)nn*DICO + d0 + kc*8) = v;
  }
}

// ---------------- Kernel 2: xp_part[ksp] = x[:, kchunk] @ Wc[kchunk, :]
// Linear [row][64k] LDS rows (128 B) + XOR slot-swizzle (slot ^= row&7) applied
// to BOTH the staging source (glds pre-swizzled global addr; ds_write slot) and
// the fragment ds_reads (rule #21 involution). glds coalescing = linear (XOR
// stays inside the row's two 64B lines); all ds_read_b128 <= 2-way (free).
__global__ void __launch_bounds__(256, 1) gemm_kernel(const float* __restrict__ x,
                                                      const ushort* __restrict__ wct,
                                                      float* __restrict__ xp) {
  __shared__ __align__(16) ushort sA[2][BM * BK];   // 16 KB each
  __shared__ __align__(16) ushort sB[2][BN * BK];   // 32 KB each
  const int tid = threadIdx.x;
  const int bid = blockIdx.x;                        // 256 blocks
  const int swzb = (bid & 7) * 32 + (bid >> 3);      // XCD-contiguous (256%8==0)
  const int mt = swzb & 127, ksp = swzb >> 7;        // whole XCD shares ksp (B L2-resident)
  const size_t rowbase = (size_t)mt * BM;
  const int kbase = ksp * KCHUNK;

  const int lane = tid & 63, wid = tid >> 6;
  const int l15 = lane & 15, lc = lane >> 4;

  // A staging: thread owns rows r0 and r0+64, 16-float k-chunk c0
  const int r0 = tid >> 2, c0 = tid & 3;
  const float* ag0 = x + (rowbase + r0) * (size_t)DICO + kbase + c0 * 16;
  const float* ag1 = ag0 + (size_t)64 * DICO;
  const int sx0 = (((2*c0    ) ^ (r0 & 7)) * 16);    // swizzled byte slot, w0
  const int sx1 = (((2*c0 + 1) ^ (r0 & 7)) * 16);    // swizzled byte slot, w1

  // fragment-read swizzled slot bytes (row&7 == l15&7 for all frag rows)
  const int sw0 = (((    lc) ^ (l15 & 7)) * 16);     // k2=0
  const int sw1 = (((4 + lc) ^ (l15 & 7)) * 16);     // k2=1

  const char* wb = (const char*)wct;
  const size_t kb2 = (size_t)kbase * 2;

  // B staging: round r covers rows r*32+(tid>>3), slot tid&7 (linear dest)
  const int brow_s = (tid >> 3);
  const int bslot_s = tid & 7;

  f32x4 acc[8][4];
  #pragma unroll
  for (int m = 0; m < 8; ++m)
    #pragma unroll
    for (int n = 0; n < 4; ++n) acc[m][n] = (f32x4){0.f, 0.f, 0.f, 0.f};

  float4 av[8];

  auto loadA = [&](int kofs) {
    #pragma unroll
    for (int q = 0; q < 4; ++q) av[q]     = *(const float4*)(ag0 + kofs + q * 4);
    #pragma unroll
    for (int q = 0; q < 4; ++q) av[4 + q] = *(const float4*)(ag1 + kofs + q * 4);
  };
  auto stageB = [&](int buf, int kofs) {
    #pragma unroll
    for (int r = 0; r < 8; ++r) {
      const int row = r * 32 + brow_s;
      const int srcslot = bslot_s ^ (row & 7);       // inverse-swizzled source
      glds16(wb + (size_t)row * (DICO * 2) + kb2 + (size_t)kofs * 2 + srcslot * 16,
             (char*)&sB[buf][0] + r * 4096 + tid * 16);   // linear dest
    }
  };
  auto storeA = [&](int buf) {
    #pragma unroll
    for (int h = 0; h < 2; ++h) {
      const float4 a0 = av[h*4+0], a1 = av[h*4+1], a2 = av[h*4+2], a3 = av[h*4+3];
      bf16x8 w0, w1;
      w0[0]=(short)f2bf(a0.x); w0[1]=(short)f2bf(a0.y); w0[2]=(short)f2bf(a0.z); w0[3]=(short)f2bf(a0.w);
      w0[4]=(short)f2bf(a1.x); w0[5]=(short)f2bf(a1.y); w0[6]=(short)f2bf(a1.z); w0[7]=(short)f2bf(a1.w);
      w1[0]=(short)f2bf(a2.x); w1[1]=(short)f2bf(a2.y); w1[2]=(short)f2bf(a2.z); w1[3]=(short)f2bf(a2.w);
      w1[4]=(short)f2bf(a3.x); w1[5]=(short)f2bf(a3.y); w1[6]=(short)f2bf(a3.z); w1[7]=(short)f2bf(a3.w);
      char* base = (char*)&sA[buf][0] + (h ? (r0 + 64) : r0) * 128;
      *(bf16x8*)(base + sx0) = w0;
      *(bf16x8*)(base + sx1) = w1;
    }
  };
  auto compute = [&](int buf) {
    bf16x8 bfr[4][2];
    #pragma unroll
    for (int n = 0; n < 4; ++n) {
      const char* bb = (const char*)&sB[buf][0] + (wid*64 + n*16 + l15) * 128;
      bfr[n][0] = *(const bf16x8*)(bb + sw0);
      bfr[n][1] = *(const bf16x8*)(bb + sw1);
    }
    #pragma unroll
    for (int m = 0; m < 8; ++m) {
      const char* ab = (const char*)&sA[buf][0] + (m*16 + l15) * 128;
      bf16x8 a0 = *(const bf16x8*)(ab + sw0);
      bf16x8 a1 = *(const bf16x8*)(ab + sw1);
      #pragma unroll
      for (int n = 0; n < 4; ++n) {
        acc[m][n] = __builtin_amdgcn_mfma_f32_16x16x32_bf16(a0, bfr[n][0], acc[m][n], 0, 0, 0);
        acc[m][n] = __builtin_amdgcn_mfma_f32_16x16x32_bf16(a1, bfr[n][1], acc[m][n], 0, 0, 0);
      }
    }
  };

  // prologue
  loadA(0);
  stageB(0, 0);
  storeA(0);
  __syncthreads();

  int cur = 0;
  for (int ks = 0; ks < NKS; ++ks) {
    const int kn = (ks + 1) * BK;
    if (ks + 1 < NKS) { loadA(kn); stageB(cur ^ 1, kn); }  // A first in vmcnt FIFO
    compute(cur);
    if (ks + 1 < NKS) storeA(cur ^ 1);                      // waits A loads only
    __syncthreads();                                        // drains glds for next step
    cur ^= 1;
  }

  float* xpo = xp + ((size_t)ksp * M_DIM + rowbase) * LAT;
  #pragma unroll
  for (int m = 0; m < 8; ++m)
    #pragma unroll
    for (int n = 0; n < 4; ++n)
      #pragma unroll
      for (int j = 0; j < 4; ++j)
        xpo[(size_t)(m*16 + lc*4 + j) * LAT + wid*64 + n*16 + l15] = acc[m][n][j];
}

// ---------------- Kernel 3: per-b recurrence h = tanh(xp_t + bc + h@Wh)
// Spill-proof redesign: 1024 threads (16 waves). Thread (q=tid>>8, l=tid&255)
// holds Wh rows [64q,64q+64) of column l -> wh[32] = 32 VGPRs (fits ANY cap).
// Partials reduced through LDS; waves 0-3 (q==0) finish tanh + state update.
// launch_bounds(1024,4) caps VGPR at 128 so all 16 waves are co-resident.
__global__ void __launch_bounds__(1024, 4) rnn_kernel(const float* __restrict__ xp,
                           const float* __restrict__ h0, const float* __restrict__ Wenc,
                           const float* __restrict__ bemb, const float* __restrict__ benc,
                           float* __restrict__ out) {
  const int b = blockIdx.x;
  const int tid = threadIdx.x;
  const int q = tid >> 8;                          // 0..3, uniform per wave
  const int l = tid & 255;
  __shared__ __align__(16) uint32_t hbuf[2][128];  // h as 256 f16, double-buffered
  __shared__ __align__(16) float part[4][256];     // per-q partial sums

  f16x2 wh[32];
  #pragma unroll
  for (int j = 0; j < 32; ++j) {
    f16x2 w;
    w[0] = (_Float16)Wenc[(size_t)(EMB + 64*q + 2*j    )*LAT + l];
    w[1] = (_Float16)Wenc[(size_t)(EMB + 64*q + 2*j + 1)*LAT + l];
    wh[j] = w;
  }
  float bc = 0.f;
  if (q == 0) {
    bc = benc[l];
    #pragma unroll 4
    for (int e = 0; e < 256; ++e) bc += bemb[e] * Wenc[e*LAT + l];
  }
  if (tid < 128) {
    f16x2 hp;
    hp[0] = (_Float16)h0[(size_t)b*LAT + 2*tid];
    hp[1] = (_Float16)h0[(size_t)b*LAT + 2*tid + 1];
    hbuf[0][tid] = __builtin_bit_cast(uint32_t, hp);
  }
  __syncthreads();                                 // one-time full drain

  const float* xpb = xp + (size_t)b*LAT + l;       // used by q==0 only
  float*       ob  = out + (size_t)b*LAT + l;
  const size_t ST = (size_t)B_DIM * LAT;           // 16384
  const size_t PO = (size_t)M_DIM * LAT;
  float xa0 = 0.f, xa1 = 0.f, xb0 = 0.f, xb1 = 0.f, xc0 = 0.f, xc1 = 0.f;
  if (q == 0) {
    xa0 = xpb[0];  xa1 = xpb[PO];
    xb0 = xpb[ST]; xb1 = xpb[ST + PO];
  }

  for (int t = 0; t < T_DIM; ++t) {
    if (q == 0 && t + 2 < T_DIM) {
      size_t ni = (size_t)(t + 2) * ST;
      xc0 = xpb[ni]; xc1 = xpb[ni + PO];           // stays in flight (raw barriers)
    }
    const uint32_t* hc = &hbuf[t & 1][q * 32];     // this q's 64-element h slice
    float s0 = 0.f, s1 = 0.f, s2 = 0.f, s3 = 0.f;
    #pragma unroll
    for (int j = 0; j < 8; ++j) {
      uint4 hv = *(const uint4*)(hc + j*4);        // uniform addr -> broadcast
      s0 = __builtin_amdgcn_fdot2(wh[j*4+0], __builtin_bit_cast(f16x2, hv.x), s0, false);
      s1 = __builtin_amdgcn_fdot2(wh[j*4+1], __builtin_bit_cast(f16x2, hv.y), s1, false);
      s2 = __builtin_amdgcn_fdot2(wh[j*4+2], __builtin_bit_cast(f16x2, hv.z), s2, false);
      s3 = __builtin_amdgcn_fdot2(wh[j*4+3], __builtin_bit_cast(f16x2, hv.w), s3, false);
    }
    float p = (s0 + s1) + (s2 + s3);
    part[q][l] = p;
    __builtin_amdgcn_sched_barrier(0);
    asm volatile("s_waitcnt lgkmcnt(0)" ::: "memory");
    __builtin_amdgcn_s_barrier();                  // partials visible (vmcnt NOT drained)
    __builtin_amdgcn_sched_barrier(0);
    if (q == 0) {                                  // wave-uniform branch
      float pre = (xa0 + xa1) + bc + ((p + part[1][l]) + (part[2][l] + part[3][l]));
      float ax = fabsf(pre);
      float e2 = __expf(-2.f * ax);
      float r  = __fdividef(1.f - e2, 1.f + e2);
      float hn = (pre < 0.f) ? -r : r;
      ob[(size_t)t * ST] = hn;                     // fire-and-forget
      ((_Float16*)&hbuf[(t + 1) & 1][0])[l] = (_Float16)hn;
    }
    __builtin_amdgcn_sched_barrier(0);
    asm volatile("s_waitcnt lgkmcnt(0)" ::: "memory");
    __builtin_amdgcn_s_barrier();                  // new h visible
    __builtin_amdgcn_sched_barrier(0);
    xa0 = xb0; xa1 = xb1; xb0 = xc0; xb1 = xc1;
  }
}

extern "C" void kernel_launch(void* const* d_in, const int* in_sizes, int n_in,
                              void* d_out, int out_size, void* d_ws, size_t ws_size,
                              hipStream_t stream) {
  const float* x    = (const float*)d_in[0];
  const float* h0   = (const float*)d_in[1];
  const float* Wemb = (const float*)d_in[2];
  const float* bemb = (const float*)d_in[3];
  const float* Wenc = (const float*)d_in[4];
  const float* benc = (const float*)d_in[5];
  float* out = (float*)d_out;

  ushort* wct = (ushort*)d_ws;                               // 4 MiB bf16 [256][8192]
  float*  xp  = (float*)((char*)d_ws + ((size_t)4 << 20));   // 2 x 16 MiB fp32 partials

  wct_kernel<<<256, 256, 0, stream>>>(Wemb, Wenc, wct);
  gemm_kernel<<<256, 256, 0, stream>>>(x, wct, xp);
  rnn_kernel<<<64, 1024, 0, stream>>>(xp, h0, Wenc, bemb, benc, out);
}